// Round 14
// baseline (97.594 us; speedup 1.0000x reference)
//
#include <hip/hip_runtime.h>
#include <stdint.h>

#define N  256
#define N2 (N * N)        // 65536
#define N3 (N * N * N)    // 16777216

#define EPS 1e-4f         // decision-uncertainty margin (>> worst-case f32 error ~2e-5)
#define CAP (4u << 20)    // marked-voxel list capacity
#define DCHUNK 8
#define NCHUNK (N / DCHUNK)  // 32

// reflect index (jnp.pad mode='reflect'): -1 -> 1, 256 -> 254
__device__ __forceinline__ int refl(int t) {
    t = (t < 0) ? -t : t;
    return (t > N - 1) ? (2 * (N - 1) - t) : t;
}

struct F4 { float v[4]; };
__device__ __forceinline__ F4 ld4(const float* p) {
    F4 r; *(float4*)r.v = *(const float4*)p; return r;
}

// DPP whole-wave shifts (verified round 11/12: absmax 0.0).
__device__ __forceinline__ float dpp_wshr1(float v) {
    const int s = __float_as_int(v);
    return __int_as_float(__builtin_amdgcn_update_dpp(s, s, 0x138, 0xf, 0xf, false));
}
__device__ __forceinline__ float dpp_wshl1(float v) {
    const int s = __float_as_int(v);
    return __int_as_float(__builtin_amdgcn_update_dpp(s, s, 0x130, 0xf, 0xf, false));
}

// ---------------------------------------------------------------------------
// K1: f32 fused Gaussian->Sobel->|grad|, rolling d-window, 4 voxels/thread,
// ZERO barriers / LDS, software-pipelined plane loads (r13 structure).
// NEW vs r13: DCHUNK 8 -> 2048 blocks (8/CU, 32 waves/CU demand) with
// unroll capped at 4 so VGPR stays ~92 (5 waves/SIMD cap, 20/CU resident
// vs r13's 16). r10's DCHUNK-8 failure was VGPR 104 from full unroll.
// Expression trees identical to r12/r13 => mag bitwise-identical =>
// EPS/f64-fixup certification unchanged.
// ---------------------------------------------------------------------------
__global__ __launch_bounds__(256) void mag_pf_kernel(const float* __restrict__ x,
                                                     float* __restrict__ mag,
                                                     uint32_t* __restrict__ cnt) {
    const int lane = threadIdx.x;         // 0..63
    const int ty   = threadIdx.y;         // 0..3
    const int w0   = lane << 2;
    const int lb   = blockIdx.y;          // 0..63
    const int hb   = ((lb & 7) << 3) | (lb >> 3);   // XCD-contiguous h-groups
    const int h    = (hb << 2) | ty;
    const int dlo  = blockIdx.z * DCHUNK;
    if (lane == 0 && ty == 0 && lb == 0 && blockIdx.z == 0) *cnt = 0;

    const size_t rowbase = (size_t)h * N + w0;

    if (h == 0 || h == N - 1) {           // border rows: wave-uniform early out
        const float4 z4 = make_float4(0.0f, 0.0f, 0.0f, 0.0f);
        for (int j = 0; j < DCHUNK; ++j)
            *(float4*)(mag + (size_t)(dlo + j) * N2 + rowbase) = z4;
        return;
    }

    constexpr double E1 = 0.6065306597126334236038;  // exp(-0.5)
    const float fe1   = (float)E1;
    const float finvS = (float)(1.0 / ((1.0 + 2.0 * E1) * (1.0 + 2.0 * E1) * (1.0 + 2.0 * E1)));

    const int hoff0 = refl(h - 2) * N;
    const int hoff1 = refl(h - 1) * N;
    const int hoff2 = h * N;
    const int hoff3 = refl(h + 1) * N;
    const int hoff4 = refl(h + 2) * N;

    float4 A0, A1, A2, A3, A4, B0, B1, B2, B3, B4, D0, D1, D2, D3, D4;
    F4 L0, L1, L2, L3, L4;                // prefetch buffer (one plane's 5 rows)

    auto load_plane = [&](int p) {
        const float* pz = x + (size_t)refl(p) * N2 + w0;
        L0 = ld4(pz + hoff0);
        L1 = ld4(pz + hoff1);
        L2 = ld4(pz + hoff2);
        L3 = ld4(pz + hoff3);
        L4 = ld4(pz + hoff4);
    };

    auto hred_L = [&](float4& Ar, float4& Br, float4& Dr) {
        float a[4], b[4], dd[4];
#pragma unroll
        for (int c = 0; c < 4; ++c) {
            const float s = L0.v[c] + L4.v[c], u = L1.v[c] + L3.v[c];
            const float m = u + L2.v[c], n = s + u;
            a[c]  = fmaf(fe1, fmaf(2.0f, L2.v[c], n), m);
            b[c]  = fmaf(fe1, fmaf(2.0f, m, s), fmaf(2.0f, L2.v[c], u));
            dd[c] = fmaf(fe1, L4.v[c] - L0.v[c], L3.v[c] - L1.v[c]);
        }
        Ar = make_float4(a[0], a[1], a[2], a[3]);
        Br = make_float4(b[0], b[1], b[2], b[3]);
        Dr = make_float4(dd[0], dd[1], dd[2], dd[3]);
    };

    auto process_step = [&](int d) {
        float P[3][4];
#pragma unroll
        for (int c = 0; c < 4; ++c) {
            const float* b0 = &B0.x; const float* b1 = &B1.x; const float* b2 = &B2.x;
            const float* b3 = &B3.x; const float* b4 = &B4.x;
            {
                const float s = b0[c] + b4[c], u = b1[c] + b3[c];
                P[0][c] = finvS * fmaf(fe1, fmaf(2.0f, b2[c], s + u), u + b2[c]);
            }
            const float* d0 = &D0.x; const float* d1 = &D1.x; const float* d2 = &D2.x;
            const float* d3 = &D3.x; const float* d4 = &D4.x;
            {
                const float s = d0[c] + d4[c], u = d1[c] + d3[c];
                P[1][c] = finvS * fmaf(fe1, fmaf(2.0f, d2[c], s + u), u + d2[c]);
            }
            const float* a0 = &A0.x; const float* a1 = &A1.x;
            const float* a3 = &A3.x; const float* a4 = &A4.x;
            P[2][c] = finvS * fmaf(fe1, a4[c] - a0[c], a3[c] - a1[c]);
        }

        float o[4];
#pragma unroll
        for (int ch = 0; ch < 3; ++ch) {
            float V[8];
            V[2] = P[ch][0]; V[3] = P[ch][1]; V[4] = P[ch][2]; V[5] = P[ch][3];
            const float tl0 = dpp_wshr1(P[ch][2]);   // lane-1 P.z -> w0-2
            const float tl1 = dpp_wshr1(P[ch][3]);   // lane-1 P.w -> w0-1
            const float tr0 = dpp_wshl1(P[ch][0]);   // lane+1 P.x -> w0+4
            const float tr1 = dpp_wshl1(P[ch][1]);   // lane+1 P.y -> w0+5
            V[0] = (lane == 0)  ? P[ch][2] : tl0;    // refl(-2)=2
            V[1] = (lane == 0)  ? P[ch][1] : tl1;    // refl(-1)=1
            V[6] = (lane == 63) ? P[ch][2] : tr0;    // refl(256)=254
            V[7] = (lane == 63) ? P[ch][1] : tr1;    // refl(257)=253
            if (ch == 0) {        // D_w
#pragma unroll
                for (int i = 0; i < 4; ++i)
                    o[i] = fmaf(fe1, V[i + 4] - V[i], V[i + 3] - V[i + 1]);
            } else if (ch == 1) { // B_w
#pragma unroll
                for (int i = 0; i < 4; ++i) {
                    const float s = V[i] + V[i + 4], u = V[i + 1] + V[i + 3];
                    const float gy = fmaf(fe1, fmaf(2.0f, u + V[i + 2], s), fmaf(2.0f, V[i + 2], u));
                    o[i] = fmaf(gy, gy, o[i] * o[i]);
                }
            } else {              // A_w
#pragma unroll
                for (int i = 0; i < 4; ++i) {
                    const float s = V[i] + V[i + 4], u = V[i + 1] + V[i + 3];
                    const float gz = fmaf(fe1, fmaf(2.0f, V[i + 2], s + u), u + V[i + 2]);
                    o[i] = sqrtf(fmaf(gz, gz, o[i]));
                }
            }
        }

        const bool zb = (d == 0) || (d == N - 1);
        float4 ov;
        ov.x = (zb || w0 == 0)          ? 0.0f : o[0];
        ov.y = zb                        ? 0.0f : o[1];
        ov.z = zb                        ? 0.0f : o[2];
        ov.w = (zb || w0 + 3 == N - 1)  ? 0.0f : o[3];
        *(float4*)(mag + (size_t)d * N2 + rowbase) = ov;

        A0 = A1; A1 = A2; A2 = A3; A3 = A4;
        B0 = B1; B1 = B2; B2 = B3; B3 = B4;
        D0 = D1; D1 = D2; D2 = D3; D3 = D4;
    };

    // prologue: planes dlo-2..dlo+1 direct, prefetch plane dlo+2
    load_plane(dlo - 2); hred_L(A0, B0, D0);
    load_plane(dlo - 1); hred_L(A1, B1, D1);
    load_plane(dlo);     hred_L(A2, B2, D2);
    load_plane(dlo + 1); hred_L(A3, B3, D3);
    load_plane(dlo + 2);

#pragma unroll 4
    for (int j = 0; j < DCHUNK - 1; ++j) {
        hred_L(A4, B4, D4);
        load_plane(dlo + j + 3);
        process_step(dlo + j);
    }
    // peeled last iteration (no prefetch)
    hred_L(A4, B4, D4);
    process_step(dlo + DCHUNK - 1);
}

// ---------------------------------------------------------------------------
// K2: NMS + double threshold, 4 voxels/thread (round-6 verified).
// ---------------------------------------------------------------------------
__global__ __launch_bounds__(256) void nms4_kernel(const float* __restrict__ mag,
                                                   uint8_t* __restrict__ flags,
                                                   uint32_t* __restrict__ cnt,
                                                   uint32_t* __restrict__ list) {
    const int tx = threadIdx.x;        // 0..63
    const int ty = threadIdx.y;        // 0..3
    const int w0 = tx << 2;
    const int h  = (blockIdx.y << 2) | ty;
    const int d  = blockIdx.z;
    const size_t base = (size_t)d * N2 + (size_t)h * N + w0;

    if (d == 0 || d == N - 1 || h == 0 || h == N - 1) {
        *(uchar4*)(flags + base) = make_uchar4(0, 0, 0, 0);
        return;
    }

    const F4 Cq = ld4(mag + base);
    const int Loff = (tx == 0) ? 0 : -4;   // avoid OOB-below; L only feeds masked w=0

    float Vm[12], Vc[12], Vp[12];
    {
        const float* rm = mag + base - N2 - N;
        const float* rc = mag + base - N2;
        const float* rp = mag + base - N2 + N;
        const F4 a0 = ld4(rm + Loff), a1 = ld4(rm), a2 = ld4(rm + 4);
        const F4 b0 = ld4(rc + Loff), b1 = ld4(rc), b2 = ld4(rc + 4);
        const F4 c0 = ld4(rp + Loff), c1 = ld4(rp), c2 = ld4(rp + 4);
#pragma unroll
        for (int k = 0; k < 4; ++k) {
            Vm[k] = a0.v[k]; Vm[k + 4] = a1.v[k]; Vm[k + 8] = a2.v[k];
            Vc[k] = b0.v[k]; Vc[k + 4] = b1.v[k]; Vc[k + 8] = b2.v[k];
            Vp[k] = c0.v[k]; Vp[k + 4] = c1.v[k]; Vp[k + 8] = c2.v[k];
        }
    }

    uint8_t fq[4];
#pragma unroll
    for (int i = 0; i < 4; ++i) {
        const int w = w0 + i;
        uint8_t f = 0;
        if (w > 0 && w < N - 1) {
            const float m0 = Cq.v[i];
            float mn = m0 - Vm[i + 3];
            mn = fminf(mn, m0 - Vm[i + 4]);
            mn = fminf(mn, m0 - Vm[i + 5]);
            mn = fminf(mn, m0 - Vc[i + 3]);
            mn = fminf(mn, m0 - Vc[i + 5]);
            mn = fminf(mn, m0 - Vp[i + 3]);
            mn = fminf(mn, m0 - Vp[i + 4]);
            mn = fminf(mn, m0 - Vp[i + 5]);
            const bool keep = mn > 0.0f;
            if (keep) f = (m0 > 0.2f) ? 2 : ((m0 > 0.1f) ? 1 : 0);
            const bool uncertain = (mn > -EPS) &&
                ((mn <= EPS) || (keep && (fabsf(m0 - 0.2f) < EPS || fabsf(m0 - 0.1f) < EPS)));
            if (uncertain) {
                const uint32_t pos = atomicAdd(cnt, 1u);
                if (pos < CAP) list[pos] = (uint32_t)(base + i);
            }
        }
        fq[i] = f;
    }
    *(uchar4*)(flags + base) = make_uchar4(fq[0], fq[1], fq[2], fq[3]);
}

// ---------------------------------------------------------------------------
// K2b: exact-f64 re-decision, one marked voxel per WAVEFRONT (round-4 verified).
// ---------------------------------------------------------------------------
__global__ __launch_bounds__(256) void fixup_wave_kernel(const float* __restrict__ x,
                                                         const uint32_t* __restrict__ cnt,
                                                         const uint32_t* __restrict__ list,
                                                         uint8_t* __restrict__ flags) {
    const uint32_t n = min(*cnt, CAP);
    const int lane = threadIdx.x & 63;
    const uint32_t wave = (blockIdx.x * blockDim.x + threadIdx.x) >> 6;
    const uint32_t nwaves = (gridDim.x * blockDim.x) >> 6;

    const int dy_t[9] = { 0, -1, -1, -1,  0, 0,  1, 1, 1 };
    const int dz_t[9] = { 0, -1,  0,  1, -1, 1, -1, 0, 1 };

    const int e_raw = lane / 5;            // 0..12
    const int a     = lane - e_raw * 5;    // 0..4
    const bool lane_valid = (e_raw < 9);
    const int e = lane_valid ? e_raw : 0;

    const double e1 = 0.6065306597126334236038;  // exp(-0.5)
    const double A[5]  = { e1, 1.0 + e1, 1.0 + 2.0 * e1, 1.0 + e1, e1 };
    const double B[5]  = { e1, 1.0 + 2.0 * e1, 2.0 + 2.0 * e1, 1.0 + 2.0 * e1, e1 };
    const double Dk[5] = { -e1, -1.0, 0.0, 1.0, e1 };
    const double s1 = 1.0 + 2.0 * e1;
    const double invS = 1.0 / (s1 * s1 * s1);

    for (uint32_t v = wave; v < n; v += nwaves) {
        const uint32_t idx = list[v];
        const int w0 = idx & (N - 1);
        const int h0 = (idx >> 8) & (N - 1);
        const int d0 = (int)(idx >> 16);

        const int pd = (e == 0) ? d0 : d0 - 1;
        const int ph = h0 + dy_t[e];
        const int pw = w0 + dz_t[e];
        const bool border = !lane_valid ||
            (pd == 0 || pd == N - 1 || ph == 0 || ph == N - 1 || pw == 0 || pw == N - 1);

        double pgx = 0.0, pgy = 0.0, pgz = 0.0;
        if (!border) {
            const float* pz = x + (size_t)refl(pd - 2 + a) * N2;
            int wi[5];
#pragma unroll
            for (int c = 0; c < 5; ++c) wi[c] = refl(pw - 2 + c);
#pragma unroll
            for (int b = 0; b < 5; ++b) {
                const float* py = pz + (size_t)refl(ph - 2 + b) * N;
                double rA = 0.0, rB = 0.0, rD = 0.0;
#pragma unroll
                for (int c = 0; c < 5; ++c) {
                    const double vv = (double)py[wi[c]];
                    rA += A[c] * vv; rB += B[c] * vv; rD += Dk[c] * vv;
                }
                pgx += A[a]  * B[b]  * rD;
                pgy += A[a]  * Dk[b] * rB;
                pgz += Dk[a] * A[b]  * rA;
            }
        }

        double sgx = pgx, sgy = pgy, sgz = pgz;
#pragma unroll
        for (int off = 1; off < 5; ++off) {
            sgx += __shfl_down(pgx, off);
            sgy += __shfl_down(pgy, off);
            sgz += __shfl_down(pgz, off);
        }
        double m = 0.0;
        if (!border && a == 0) {
            sgx *= invS; sgy *= invS; sgz *= invS;
            m = sqrt(sgx * sgx + sgy * sgy + sgz * sgz);
        }

        const double m0 = __shfl(m, 0);
        bool keep = true;
#pragma unroll
        for (int e2 = 1; e2 < 9; ++e2) {
            const double nb = __shfl(m, 5 * e2);
            keep = keep && (m0 > nb);
        }
        if (lane == 0) {
            uint8_t f = 0;
            if (keep) f = (m0 > 0.2) ? 2 : ((m0 > 0.1) ? 1 : 0);
            flags[idx] = f;
        }
    }
}

// ---------------------------------------------------------------------------
// K3: hysteresis, 4 voxels per thread (round-4 verified).
// ---------------------------------------------------------------------------
__global__ __launch_bounds__(256) void hyst4_kernel(const uint8_t* __restrict__ flags,
                                                    int* __restrict__ out) {
    const int w4 = threadIdx.x * 4;                    // 0..252, x-dim = 64
    const int h  = blockIdx.y * 4 + threadIdx.y;       // y-dim = 4
    const int d  = blockIdx.z;
    const size_t base = (size_t)d * N2 + (size_t)h * N + w4;

    const uchar4 f4 = *(const uchar4*)(flags + base);
    const uint8_t f[4] = { f4.x, f4.y, f4.z, f4.w };
    int r[4];
#pragma unroll
    for (int i = 0; i < 4; ++i) {
        int rr = 0;
        if (f[i] == 2) {
            rr = 1;
        } else if (f[i] == 1) {  // weak implies interior: all 6 nbrs in-bounds
            const size_t idx = base + i;
            if (flags[idx - N2] == 2 || flags[idx + N2] == 2 ||
                flags[idx - N]  == 2 || flags[idx + N]  == 2 ||
                flags[idx - 1]  == 2 || flags[idx + 1]  == 2)
                rr = 1;
        }
        r[i] = rr;
    }
    *(int4*)(out + base) = make_int4(r[0], r[1], r[2], r[3]);
}

extern "C" void kernel_launch(void* const* d_in, const int* in_sizes, int n_in,
                              void* d_out, int out_size, void* d_ws, size_t ws_size,
                              hipStream_t stream) {
    const float* x = (const float*)d_in[0];
    int* out = (int*)d_out;

    // ws layout: [0,64MiB) f32 mag; [64,80MiB) u8 flags; 80MiB: u32 counter;
    //            [80MiB+64B, +16MiB) u32 marked-voxel list
    float*    mag   = (float*)d_ws;
    uint8_t*  flags = (uint8_t*)d_ws + (size_t)N3 * 4;
    uint32_t* cnt   = (uint32_t*)((char*)d_ws + (size_t)N3 * 5);
    uint32_t* list  = (uint32_t*)((char*)d_ws + (size_t)N3 * 5 + 64);

    mag_pf_kernel<<<dim3(1, 64, NCHUNK), dim3(64, 4, 1), 0, stream>>>(x, mag, cnt);
    nms4_kernel<<<dim3(1, 64, N), dim3(64, 4, 1), 0, stream>>>(mag, flags, cnt, list);
    fixup_wave_kernel<<<dim3(1024), dim3(256), 0, stream>>>(x, cnt, list, flags);
    hyst4_kernel<<<dim3(1, 64, N), dim3(64, 4, 1), 0, stream>>>(flags, out);
}

// Round 15
// 90.576 us; speedup vs baseline: 1.0775x; 1.0775x over previous
//
#include <hip/hip_runtime.h>
#include <stdint.h>

#define N  256
#define N2 (N * N)        // 65536
#define N3 (N * N * N)    // 16777216

#define EPS 1e-4f         // decision-uncertainty margin (>> worst-case f32 error ~2e-5)
#define CAP (4u << 20)    // marked-voxel list capacity
#define DCHUNK 16
#define NCHUNK (N / DCHUNK)  // 16

// reflect index (jnp.pad mode='reflect'): -1 -> 1, 256 -> 254
__device__ __forceinline__ int refl(int t) {
    t = (t < 0) ? -t : t;
    return (t > N - 1) ? (2 * (N - 1) - t) : t;
}

struct F4 { float v[4]; };
__device__ __forceinline__ F4 ld4(const float* p) {
    F4 r; *(float4*)r.v = *(const float4*)p; return r;
}

// DPP whole-wave shifts (verified rounds 11/12: absmax 0.0).
__device__ __forceinline__ float dpp_wshr1(float v) {
    const int s = __float_as_int(v);
    return __int_as_float(__builtin_amdgcn_update_dpp(s, s, 0x138, 0xf, 0xf, false));
}
__device__ __forceinline__ float dpp_wshl1(float v) {
    const int s = __float_as_int(v);
    return __int_as_float(__builtin_amdgcn_update_dpp(s, s, 0x130, 0xf, 0xf, false));
}

// ---------------------------------------------------------------------------
// K1: f32 fused Gaussian->Sobel->|grad|, rolling d-window, 4 voxels/thread,
// ZERO barriers / LDS / lgkmcnt. Best-measured config (round 12: mag ~50us,
// VGPR 76, no spill): DCHUNK 16, 1024 blocks, unroll 8, plain launch bounds
// (NO min-waves bound: r11's (256,6) forced VGPR 40 and spilled wholesale).
// Halo exchange on DPP wave-shifts; lane 0/63 use own reflect columns.
// Ladder of failed alternatives (for the record): LDS+barrier 2-wide (60us,
// barrier drain), DCHUNK 8 variants (57us, occupancy pinned ~17% regardless
// of grid), explicit prefetch pipeline (flat: +VALU copies, same stall).
// EPS/f64-fixup certification: non-marked decisions provably match f64.
// ---------------------------------------------------------------------------
__global__ __launch_bounds__(256) void mag_dpp_kernel(const float* __restrict__ x,
                                                      float* __restrict__ mag,
                                                      uint32_t* __restrict__ cnt) {
    const int lane = threadIdx.x;         // 0..63
    const int ty   = threadIdx.y;         // 0..3
    const int w0   = lane << 2;
    const int lb   = blockIdx.y;          // 0..63
    const int hb   = ((lb & 7) << 3) | (lb >> 3);   // XCD-contiguous h-groups
    const int h    = (hb << 2) | ty;
    const int dlo  = blockIdx.z * DCHUNK;
    if (lane == 0 && ty == 0 && lb == 0 && blockIdx.z == 0) *cnt = 0;

    const size_t rowbase = (size_t)h * N + w0;

    if (h == 0 || h == N - 1) {           // border rows: wave-uniform early out
        const float4 z4 = make_float4(0.0f, 0.0f, 0.0f, 0.0f);
        for (int j = 0; j < DCHUNK; ++j)
            *(float4*)(mag + (size_t)(dlo + j) * N2 + rowbase) = z4;
        return;
    }

    constexpr double E1 = 0.6065306597126334236038;  // exp(-0.5)
    const float fe1   = (float)E1;
    const float finvS = (float)(1.0 / ((1.0 + 2.0 * E1) * (1.0 + 2.0 * E1) * (1.0 + 2.0 * E1)));

    const int hoff0 = refl(h - 2) * N;
    const int hoff1 = refl(h - 1) * N;
    const int hoff2 = h * N;
    const int hoff3 = refl(h + 1) * N;
    const int hoff4 = refl(h + 2) * N;

    float4 A0, A1, A2, A3, A4, B0, B1, B2, B3, B4, D0, D1, D2, D3, D4;

    auto hred = [&](int p, float4& Ar, float4& Br, float4& Dr) {
        const float* pz = x + (size_t)refl(p) * N2 + w0;
        const F4 v0 = ld4(pz + hoff0);
        const F4 v1 = ld4(pz + hoff1);
        const F4 v2 = ld4(pz + hoff2);
        const F4 v3 = ld4(pz + hoff3);
        const F4 v4 = ld4(pz + hoff4);
        float a[4], b[4], dd[4];
#pragma unroll
        for (int c = 0; c < 4; ++c) {
            const float s = v0.v[c] + v4.v[c], u = v1.v[c] + v3.v[c];
            const float m = u + v2.v[c], n = s + u;
            a[c]  = fmaf(fe1, fmaf(2.0f, v2.v[c], n), m);
            b[c]  = fmaf(fe1, fmaf(2.0f, m, s), fmaf(2.0f, v2.v[c], u));
            dd[c] = fmaf(fe1, v4.v[c] - v0.v[c], v3.v[c] - v1.v[c]);
        }
        Ar = make_float4(a[0], a[1], a[2], a[3]);
        Br = make_float4(b[0], b[1], b[2], b[3]);
        Dr = make_float4(dd[0], dd[1], dd[2], dd[3]);
    };

    // prologue: planes dlo-2..dlo+1
    hred(dlo - 2, A0, B0, D0);
    hred(dlo - 1, A1, B1, D1);
    hred(dlo,     A2, B2, D2);
    hred(dlo + 1, A3, B3, D3);

#pragma unroll 8
    for (int j = 0; j < DCHUNK; ++j) {
        const int d = dlo + j;
        hred(d + 2, A4, B4, D4);

        // d-combine -> P (3 channels x 4 cols), expression trees = round 5
        float P[3][4];
#pragma unroll
        for (int c = 0; c < 4; ++c) {
            const float* b0 = &B0.x; const float* b1 = &B1.x; const float* b2 = &B2.x;
            const float* b3 = &B3.x; const float* b4 = &B4.x;
            {
                const float s = b0[c] + b4[c], u = b1[c] + b3[c];
                P[0][c] = finvS * fmaf(fe1, fmaf(2.0f, b2[c], s + u), u + b2[c]);
            }
            const float* d0 = &D0.x; const float* d1 = &D1.x; const float* d2 = &D2.x;
            const float* d3 = &D3.x; const float* d4 = &D4.x;
            {
                const float s = d0[c] + d4[c], u = d1[c] + d3[c];
                P[1][c] = finvS * fmaf(fe1, fmaf(2.0f, d2[c], s + u), u + d2[c]);
            }
            const float* a0 = &A0.x; const float* a1 = &A1.x;
            const float* a3 = &A3.x; const float* a4 = &A4.x;
            P[2][c] = finvS * fmaf(fe1, a4[c] - a0[c], a3[c] - a1[c]);
        }

        // halo exchange via DPP wave-shift; lane 0/63 use own reflect columns
        float o[4];
#pragma unroll
        for (int ch = 0; ch < 3; ++ch) {
            float V[8];
            V[2] = P[ch][0]; V[3] = P[ch][1]; V[4] = P[ch][2]; V[5] = P[ch][3];
            const float tl0 = dpp_wshr1(P[ch][2]);   // lane-1 P.z -> w0-2
            const float tl1 = dpp_wshr1(P[ch][3]);   // lane-1 P.w -> w0-1
            const float tr0 = dpp_wshl1(P[ch][0]);   // lane+1 P.x -> w0+4
            const float tr1 = dpp_wshl1(P[ch][1]);   // lane+1 P.y -> w0+5
            V[0] = (lane == 0)  ? P[ch][2] : tl0;    // refl(-2)=2
            V[1] = (lane == 0)  ? P[ch][1] : tl1;    // refl(-1)=1
            V[6] = (lane == 63) ? P[ch][2] : tr0;    // refl(256)=254
            V[7] = (lane == 63) ? P[ch][1] : tr1;    // refl(257)=253
            if (ch == 0) {        // D_w
#pragma unroll
                for (int i = 0; i < 4; ++i)
                    o[i] = fmaf(fe1, V[i + 4] - V[i], V[i + 3] - V[i + 1]);
            } else if (ch == 1) { // B_w
#pragma unroll
                for (int i = 0; i < 4; ++i) {
                    const float s = V[i] + V[i + 4], u = V[i + 1] + V[i + 3];
                    const float gy = fmaf(fe1, fmaf(2.0f, u + V[i + 2], s), fmaf(2.0f, V[i + 2], u));
                    o[i] = fmaf(gy, gy, o[i] * o[i]);  // gy^2 + gx^2
                }
            } else {              // A_w
#pragma unroll
                for (int i = 0; i < 4; ++i) {
                    const float s = V[i] + V[i + 4], u = V[i + 1] + V[i + 3];
                    const float gz = fmaf(fe1, fmaf(2.0f, V[i + 2], s + u), u + V[i + 2]);
                    o[i] = sqrtf(fmaf(gz, gz, o[i]));
                }
            }
        }
        // (association differs from round-5 by <=2 ulp; EPS=1e-4 >> that, and
        // every decision within EPS is re-decided in f64 by the fixup kernel.)

        const bool zb = (d == 0) || (d == N - 1);
        float4 ov;
        ov.x = (zb || w0 == 0)          ? 0.0f : o[0];
        ov.y = zb                        ? 0.0f : o[1];
        ov.z = zb                        ? 0.0f : o[2];
        ov.w = (zb || w0 + 3 == N - 1)  ? 0.0f : o[3];
        *(float4*)(mag + (size_t)d * N2 + rowbase) = ov;

        // shift window (renamed away under unroll)
        A0 = A1; A1 = A2; A2 = A3; A3 = A4;
        B0 = B1; B1 = B2; B2 = B3; B3 = B4;
        D0 = D1; D1 = D2; D2 = D3; D3 = D4;
    }
}

// ---------------------------------------------------------------------------
// K2: NMS + double threshold, 4 voxels/thread (round-6 verified).
// ---------------------------------------------------------------------------
__global__ __launch_bounds__(256) void nms4_kernel(const float* __restrict__ mag,
                                                   uint8_t* __restrict__ flags,
                                                   uint32_t* __restrict__ cnt,
                                                   uint32_t* __restrict__ list) {
    const int tx = threadIdx.x;        // 0..63
    const int ty = threadIdx.y;        // 0..3
    const int w0 = tx << 2;
    const int h  = (blockIdx.y << 2) | ty;
    const int d  = blockIdx.z;
    const size_t base = (size_t)d * N2 + (size_t)h * N + w0;

    if (d == 0 || d == N - 1 || h == 0 || h == N - 1) {
        *(uchar4*)(flags + base) = make_uchar4(0, 0, 0, 0);
        return;
    }

    const F4 Cq = ld4(mag + base);
    const int Loff = (tx == 0) ? 0 : -4;   // avoid OOB-below; L only feeds masked w=0

    float Vm[12], Vc[12], Vp[12];
    {
        const float* rm = mag + base - N2 - N;
        const float* rc = mag + base - N2;
        const float* rp = mag + base - N2 + N;
        const F4 a0 = ld4(rm + Loff), a1 = ld4(rm), a2 = ld4(rm + 4);
        const F4 b0 = ld4(rc + Loff), b1 = ld4(rc), b2 = ld4(rc + 4);
        const F4 c0 = ld4(rp + Loff), c1 = ld4(rp), c2 = ld4(rp + 4);
#pragma unroll
        for (int k = 0; k < 4; ++k) {
            Vm[k] = a0.v[k]; Vm[k + 4] = a1.v[k]; Vm[k + 8] = a2.v[k];
            Vc[k] = b0.v[k]; Vc[k + 4] = b1.v[k]; Vc[k + 8] = b2.v[k];
            Vp[k] = c0.v[k]; Vp[k + 4] = c1.v[k]; Vp[k + 8] = c2.v[k];
        }
    }

    uint8_t fq[4];
#pragma unroll
    for (int i = 0; i < 4; ++i) {
        const int w = w0 + i;
        uint8_t f = 0;
        if (w > 0 && w < N - 1) {
            const float m0 = Cq.v[i];
            float mn = m0 - Vm[i + 3];
            mn = fminf(mn, m0 - Vm[i + 4]);
            mn = fminf(mn, m0 - Vm[i + 5]);
            mn = fminf(mn, m0 - Vc[i + 3]);
            mn = fminf(mn, m0 - Vc[i + 5]);
            mn = fminf(mn, m0 - Vp[i + 3]);
            mn = fminf(mn, m0 - Vp[i + 4]);
            mn = fminf(mn, m0 - Vp[i + 5]);
            const bool keep = mn > 0.0f;
            if (keep) f = (m0 > 0.2f) ? 2 : ((m0 > 0.1f) ? 1 : 0);
            const bool uncertain = (mn > -EPS) &&
                ((mn <= EPS) || (keep && (fabsf(m0 - 0.2f) < EPS || fabsf(m0 - 0.1f) < EPS)));
            if (uncertain) {
                const uint32_t pos = atomicAdd(cnt, 1u);
                if (pos < CAP) list[pos] = (uint32_t)(base + i);
            }
        }
        fq[i] = f;
    }
    *(uchar4*)(flags + base) = make_uchar4(fq[0], fq[1], fq[2], fq[3]);
}

// ---------------------------------------------------------------------------
// K2b: exact-f64 re-decision, one marked voxel per WAVEFRONT (round-4 verified).
// ---------------------------------------------------------------------------
__global__ __launch_bounds__(256) void fixup_wave_kernel(const float* __restrict__ x,
                                                         const uint32_t* __restrict__ cnt,
                                                         const uint32_t* __restrict__ list,
                                                         uint8_t* __restrict__ flags) {
    const uint32_t n = min(*cnt, CAP);
    const int lane = threadIdx.x & 63;
    const uint32_t wave = (blockIdx.x * blockDim.x + threadIdx.x) >> 6;
    const uint32_t nwaves = (gridDim.x * blockDim.x) >> 6;

    const int dy_t[9] = { 0, -1, -1, -1,  0, 0,  1, 1, 1 };
    const int dz_t[9] = { 0, -1,  0,  1, -1, 1, -1, 0, 1 };

    const int e_raw = lane / 5;            // 0..12
    const int a     = lane - e_raw * 5;    // 0..4
    const bool lane_valid = (e_raw < 9);
    const int e = lane_valid ? e_raw : 0;

    const double e1 = 0.6065306597126334236038;  // exp(-0.5)
    const double A[5]  = { e1, 1.0 + e1, 1.0 + 2.0 * e1, 1.0 + e1, e1 };
    const double B[5]  = { e1, 1.0 + 2.0 * e1, 2.0 + 2.0 * e1, 1.0 + 2.0 * e1, e1 };
    const double Dk[5] = { -e1, -1.0, 0.0, 1.0, e1 };
    const double s1 = 1.0 + 2.0 * e1;
    const double invS = 1.0 / (s1 * s1 * s1);

    for (uint32_t v = wave; v < n; v += nwaves) {
        const uint32_t idx = list[v];
        const int w0 = idx & (N - 1);
        const int h0 = (idx >> 8) & (N - 1);
        const int d0 = (int)(idx >> 16);

        const int pd = (e == 0) ? d0 : d0 - 1;
        const int ph = h0 + dy_t[e];
        const int pw = w0 + dz_t[e];
        const bool border = !lane_valid ||
            (pd == 0 || pd == N - 1 || ph == 0 || ph == N - 1 || pw == 0 || pw == N - 1);

        double pgx = 0.0, pgy = 0.0, pgz = 0.0;
        if (!border) {
            const float* pz = x + (size_t)refl(pd - 2 + a) * N2;
            int wi[5];
#pragma unroll
            for (int c = 0; c < 5; ++c) wi[c] = refl(pw - 2 + c);
#pragma unroll
            for (int b = 0; b < 5; ++b) {
                const float* py = pz + (size_t)refl(ph - 2 + b) * N;
                double rA = 0.0, rB = 0.0, rD = 0.0;
#pragma unroll
                for (int c = 0; c < 5; ++c) {
                    const double vv = (double)py[wi[c]];
                    rA += A[c] * vv; rB += B[c] * vv; rD += Dk[c] * vv;
                }
                pgx += A[a]  * B[b]  * rD;
                pgy += A[a]  * Dk[b] * rB;
                pgz += Dk[a] * A[b]  * rA;
            }
        }

        double sgx = pgx, sgy = pgy, sgz = pgz;
#pragma unroll
        for (int off = 1; off < 5; ++off) {
            sgx += __shfl_down(pgx, off);
            sgy += __shfl_down(pgy, off);
            sgz += __shfl_down(pgz, off);
        }
        double m = 0.0;
        if (!border && a == 0) {
            sgx *= invS; sgy *= invS; sgz *= invS;
            m = sqrt(sgx * sgx + sgy * sgy + sgz * sgz);
        }

        const double m0 = __shfl(m, 0);
        bool keep = true;
#pragma unroll
        for (int e2 = 1; e2 < 9; ++e2) {
            const double nb = __shfl(m, 5 * e2);
            keep = keep && (m0 > nb);
        }
        if (lane == 0) {
            uint8_t f = 0;
            if (keep) f = (m0 > 0.2) ? 2 : ((m0 > 0.1) ? 1 : 0);
            flags[idx] = f;
        }
    }
}

// ---------------------------------------------------------------------------
// K3: hysteresis, 4 voxels per thread (round-4 verified).
// ---------------------------------------------------------------------------
__global__ __launch_bounds__(256) void hyst4_kernel(const uint8_t* __restrict__ flags,
                                                    int* __restrict__ out) {
    const int w4 = threadIdx.x * 4;                    // 0..252, x-dim = 64
    const int h  = blockIdx.y * 4 + threadIdx.y;       // y-dim = 4
    const int d  = blockIdx.z;
    const size_t base = (size_t)d * N2 + (size_t)h * N + w4;

    const uchar4 f4 = *(const uchar4*)(flags + base);
    const uint8_t f[4] = { f4.x, f4.y, f4.z, f4.w };
    int r[4];
#pragma unroll
    for (int i = 0; i < 4; ++i) {
        int rr = 0;
        if (f[i] == 2) {
            rr = 1;
        } else if (f[i] == 1) {  // weak implies interior: all 6 nbrs in-bounds
            const size_t idx = base + i;
            if (flags[idx - N2] == 2 || flags[idx + N2] == 2 ||
                flags[idx - N]  == 2 || flags[idx + N]  == 2 ||
                flags[idx - 1]  == 2 || flags[idx + 1]  == 2)
                rr = 1;
        }
        r[i] = rr;
    }
    *(int4*)(out + base) = make_int4(r[0], r[1], r[2], r[3]);
}

extern "C" void kernel_launch(void* const* d_in, const int* in_sizes, int n_in,
                              void* d_out, int out_size, void* d_ws, size_t ws_size,
                              hipStream_t stream) {
    const float* x = (const float*)d_in[0];
    int* out = (int*)d_out;

    // ws layout: [0,64MiB) f32 mag; [64,80MiB) u8 flags; 80MiB: u32 counter;
    //            [80MiB+64B, +16MiB) u32 marked-voxel list
    float*    mag   = (float*)d_ws;
    uint8_t*  flags = (uint8_t*)d_ws + (size_t)N3 * 4;
    uint32_t* cnt   = (uint32_t*)((char*)d_ws + (size_t)N3 * 5);
    uint32_t* list  = (uint32_t*)((char*)d_ws + (size_t)N3 * 5 + 64);

    mag_dpp_kernel<<<dim3(1, 64, NCHUNK), dim3(64, 4, 1), 0, stream>>>(x, mag, cnt);
    nms4_kernel<<<dim3(1, 64, N), dim3(64, 4, 1), 0, stream>>>(mag, flags, cnt, list);
    fixup_wave_kernel<<<dim3(512), dim3(256), 0, stream>>>(x, cnt, list, flags);
    hyst4_kernel<<<dim3(1, 64, N), dim3(64, 4, 1), 0, stream>>>(flags, out);
}